// Round 8
// baseline (433.180 us; speedup 1.0000x reference)
//
#include <hip/hip_runtime.h>
#include <math.h>

#define H 1024
#define V 128000
#define G3H 3072     // 3*H

#define NBLK    1024                // 4 blocks/CU x 256 CU -> exactly co-resident
#define NWAVES  (NBLK * 4)          // 4096 waves
#define NGROUPS (V / 4)             // 32000 groups of 4 rows
#define NPART   NBLK                // one (m,S) pair per block

// ws layout (floats):
//   [0 .. 6143]           gi (3072) then gh (3072)
//   [8192 .. 8192+2047]   per-block (m, S) partials
//   [10240 .. 10241]      barrier counters (memset to 0 each launch)
#define WS_GI   0
#define WS_GH   G3H
#define WS_PART 8192
#define WS_BAR  10240

typedef float f32x4 __attribute__((ext_vector_type(4)));

#define DOT4(w_, x_) fmaf((w_).x,(x_).x, fmaf((w_).y,(x_).y, fmaf((w_).z,(x_).z, (w_).w*(x_).w)))

__device__ __forceinline__ float sigmoid_fast(float x) {
  return 1.f / (1.f + __expf(-x));
}
__device__ __forceinline__ float tanh_fast(float x) {
  return 1.f - 2.f / (__expf(2.f * x) + 1.f);   // overflow-safe tanh
}

// Grid barrier for an exactly-co-resident grid.
// Release: syncthreads (drains stores to L2) + threadfence + agent ACQ_REL add
//          (L2 writeback to coherence point on gfx95x).
// Acquire: agent ACQUIRE spin load + trailing threadfence (L2/L1 invalidate).
// Timeout insurance (~40 ms) turns a co-residency failure into a visible
// correctness fail instead of a hang.
__device__ __forceinline__ void grid_barrier(unsigned int* cnt) {
  __syncthreads();
  if (threadIdx.x == 0) {
    __threadfence();
    __hip_atomic_fetch_add(cnt, 1u, __ATOMIC_ACQ_REL, __HIP_MEMORY_SCOPE_AGENT);
    const unsigned long long t0 = __builtin_amdgcn_s_memrealtime();
    while (__hip_atomic_load(cnt, __ATOMIC_ACQUIRE, __HIP_MEMORY_SCOPE_AGENT) < NBLK) {
      __builtin_amdgcn_s_sleep(2);
      if (__builtin_amdgcn_s_memrealtime() - t0 > 4000000ULL) break;  // ~40 ms @100MHz
    }
    __threadfence();
  }
  __syncthreads();
}

// ================= fused: gates -> h1 -> logits -> LSE -> normalize =================
__global__ __launch_bounds__(256, 4) void decoder_fused(
    const int* __restrict__ ids, const float* __restrict__ hidden,
    const float* __restrict__ emb,
    const float* __restrict__ W_ih, const float* __restrict__ W_hh,
    const float* __restrict__ b_ih, const float* __restrict__ b_hh,
    const float* __restrict__ W_out, const float* __restrict__ b_out,
    float* __restrict__ d_out, float* __restrict__ ws) {
  __shared__ __align__(16) f32x4 h1s4[256];
  __shared__ float wpm[4], wps[4];
  __shared__ float redm[256], reds[256];

  const int tid  = threadIdx.x;
  const int lane = tid & 63;
  const int wid  = blockIdx.x * 4 + (tid >> 6);   // 0..4095
  unsigned int* bar = (unsigned int*)(ws + WS_BAR);

  // ---------------- Phase A: gates (waves 0..3071, 2 rows each) ----------------
  if (wid < 3072) {
    const bool isGi = (wid < 1536);
    const int row0 = (isGi ? wid : wid - 1536) * 2;
    const float* Wm = isGi ? W_ih : W_hh;
    const float* xp = isGi ? (emb + (size_t)ids[0] * H) : hidden;

    f32x4 x0 = ((const f32x4*)xp)[lane];
    f32x4 x1 = ((const f32x4*)xp)[lane + 64];
    f32x4 x2 = ((const f32x4*)xp)[lane + 128];
    f32x4 x3 = ((const f32x4*)xp)[lane + 192];
    if (isGi) {
      x0.x=fmaxf(x0.x,0.f); x0.y=fmaxf(x0.y,0.f); x0.z=fmaxf(x0.z,0.f); x0.w=fmaxf(x0.w,0.f);
      x1.x=fmaxf(x1.x,0.f); x1.y=fmaxf(x1.y,0.f); x1.z=fmaxf(x1.z,0.f); x1.w=fmaxf(x1.w,0.f);
      x2.x=fmaxf(x2.x,0.f); x2.y=fmaxf(x2.y,0.f); x2.z=fmaxf(x2.z,0.f); x2.w=fmaxf(x2.w,0.f);
      x3.x=fmaxf(x3.x,0.f); x3.y=fmaxf(x3.y,0.f); x3.z=fmaxf(x3.z,0.f); x3.w=fmaxf(x3.w,0.f);
    }

    const f32x4* wa = (const f32x4*)(Wm + (size_t)row0 * H);
    const f32x4* wb = (const f32x4*)(Wm + (size_t)(row0 + 1) * H);
    const f32x4 a0 = __builtin_nontemporal_load(wa + lane);
    const f32x4 a1 = __builtin_nontemporal_load(wa + lane + 64);
    const f32x4 a2 = __builtin_nontemporal_load(wa + lane + 128);
    const f32x4 a3 = __builtin_nontemporal_load(wa + lane + 192);
    const f32x4 b0 = __builtin_nontemporal_load(wb + lane);
    const f32x4 b1 = __builtin_nontemporal_load(wb + lane + 64);
    const f32x4 b2 = __builtin_nontemporal_load(wb + lane + 128);
    const f32x4 b3 = __builtin_nontemporal_load(wb + lane + 192);
    float pa = (DOT4(a0,x0) + DOT4(a1,x1)) + (DOT4(a2,x2) + DOT4(a3,x3));
    float pb = (DOT4(b0,x0) + DOT4(b1,x1)) + (DOT4(b2,x2) + DOT4(b3,x3));
#pragma unroll
    for (int off = 1; off < 64; off <<= 1) {
      pa += __shfl_xor(pa, off);
      pb += __shfl_xor(pb, off);
    }
    if (lane < 2) {
      const int row = row0 + lane;
      const float s = (lane == 0) ? pa : pb;
      if (isGi) ws[WS_GI + row] = s + b_ih[row];
      else      ws[WS_GH + row] = s + b_hh[row];
    }
  }

  grid_barrier(bar);   // gi/gh written back + visible device-wide

  // ---------------- Phase B: h1 recompute + logits stream ----------------
  {
    const f32x4* ws4 = (const f32x4*)ws;
    const f32x4 gi0 = ws4[tid];          // gi[0:H]
    const f32x4 gi1 = ws4[tid + 256];    // gi[H:2H]
    const f32x4 gi2 = ws4[tid + 512];    // gi[2H:3H]
    const f32x4 gh0 = ws4[tid + 768];    // gh[0:H]
    const f32x4 gh1 = ws4[tid + 1024];   // gh[H:2H]
    const f32x4 gh2 = ws4[tid + 1280];   // gh[2H:3H]
    const f32x4 h0v = ((const f32x4*)hidden)[tid];
    f32x4 h1;
#pragma unroll
    for (int j = 0; j < 4; ++j) {
      const float r = sigmoid_fast(gi0[j] + gh0[j]);
      const float z = sigmoid_fast(gi1[j] + gh1[j]);
      const float n = tanh_fast(gi2[j] + r * gh2[j]);
      h1[j] = (1.f - z) * n + z * h0v[j];
    }
    h1s4[tid] = h1;
  }
  __syncthreads();
  if (blockIdx.x == 0) {
    ((f32x4*)(d_out + V))[tid] = h1s4[tid];
  }

  const int gbeg = (wid * NGROUPS) >> 12;       // balanced contiguous ranges
  const int gend = ((wid + 1) * NGROUPS) >> 12;

  const f32x4 x0 = h1s4[lane];
  const f32x4 x1 = h1s4[lane + 64];
  const f32x4 x2 = h1s4[lane + 128];
  const f32x4 x3 = h1s4[lane + 192];

  float m = -INFINITY, S = 0.f;

#pragma unroll 1
  for (int g = gbeg; g < gend; ++g) {
    const int row0 = g * 4;
    const f32x4* w = (const f32x4*)(W_out + (size_t)row0 * H);  // 4 rows x 256 quads

    const f32x4 a0 = __builtin_nontemporal_load(w + lane);
    const f32x4 a1 = __builtin_nontemporal_load(w + lane + 64);
    const f32x4 a2 = __builtin_nontemporal_load(w + lane + 128);
    const f32x4 a3 = __builtin_nontemporal_load(w + lane + 192);
    const f32x4 b0 = __builtin_nontemporal_load(w + lane + 256);
    const f32x4 b1 = __builtin_nontemporal_load(w + lane + 320);
    const f32x4 b2 = __builtin_nontemporal_load(w + lane + 384);
    const f32x4 b3 = __builtin_nontemporal_load(w + lane + 448);
    const f32x4 c0 = __builtin_nontemporal_load(w + lane + 512);
    const f32x4 c1 = __builtin_nontemporal_load(w + lane + 576);
    const f32x4 c2 = __builtin_nontemporal_load(w + lane + 640);
    const f32x4 c3 = __builtin_nontemporal_load(w + lane + 704);
    const f32x4 d0 = __builtin_nontemporal_load(w + lane + 768);
    const f32x4 d1 = __builtin_nontemporal_load(w + lane + 832);
    const f32x4 d2 = __builtin_nontemporal_load(w + lane + 896);
    const f32x4 d3 = __builtin_nontemporal_load(w + lane + 960);

    float p0 = (DOT4(a0,x0) + DOT4(a1,x1)) + (DOT4(a2,x2) + DOT4(a3,x3));
    float p1 = (DOT4(b0,x0) + DOT4(b1,x1)) + (DOT4(b2,x2) + DOT4(b3,x3));
    float p2 = (DOT4(c0,x0) + DOT4(c1,x1)) + (DOT4(c2,x2) + DOT4(c3,x3));
    float p3 = (DOT4(d0,x0) + DOT4(d1,x1)) + (DOT4(d2,x2) + DOT4(d3,x3));

#pragma unroll
    for (int off = 1; off < 64; off <<= 1) {
      p0 += __shfl_xor(p0, off);
      p1 += __shfl_xor(p1, off);
      p2 += __shfl_xor(p2, off);
      p3 += __shfl_xor(p3, off);
    }

    const float4 bo = *(const float4*)(b_out + row0);
    const float l0 = p0 + bo.x, l1 = p1 + bo.y, l2 = p2 + bo.z, l3 = p3 + bo.w;

    const float sel = (lane == 0) ? l0 : (lane == 1) ? l1 : (lane == 2) ? l2 : l3;
    if (lane < 4) d_out[row0 + lane] = sel;

    const float m4 = fmaxf(fmaxf(l0, l1), fmaxf(l2, l3));
    const float mn = fmaxf(m, m4);
    S = S * __expf(m - mn)
      + __expf(l0 - mn) + __expf(l1 - mn) + __expf(l2 - mn) + __expf(l3 - mn);
    m = mn;
  }

  // block's 4 wave partials -> 1 pair per block
  if (lane == 0) { wpm[tid >> 6] = m; wps[tid >> 6] = S; }
  __syncthreads();
  if (tid == 0) {
    float bm = wpm[0], bS = wps[0];
#pragma unroll
    for (int k = 1; k < 4; ++k) {
      const float mk = wpm[k], sk = wps[k];
      const float mn = fmaxf(bm, mk);
      bS = bS * __expf(bm - mn) + sk * __expf(mk - mn);
      bm = mn;
    }
    ws[WS_PART + 2 * blockIdx.x]     = bm;
    ws[WS_PART + 2 * blockIdx.x + 1] = bS;
  }

  grid_barrier(bar + 1);   // all partials written back + visible

  // ---------------- Phase C: fold partials, normalize own rows ----------------
  {
    float fm = -INFINITY, fS = 0.f;
#pragma unroll
    for (int k = 0; k < NPART / 256; ++k) {   // 4 pairs/thread
      const int b = tid + k * 256;
      const float mb = ws[WS_PART + 2*b], sb = ws[WS_PART + 2*b + 1];
      const float mn = fmaxf(fm, mb);
      fS = fS * __expf(fm - mn) + sb * __expf(mb - mn);
      fm = mn;
    }
    redm[tid] = fm; reds[tid] = fS;
    __syncthreads();
    for (int s = 128; s > 0; s >>= 1) {
      if (tid < s) {
        const float m2 = redm[tid + s], s2 = reds[tid + s];
        const float mn = fmaxf(redm[tid], m2);
        reds[tid] = reds[tid] * __expf(redm[tid] - mn) + s2 * __expf(m2 - mn);
        redm[tid] = mn;
      }
      __syncthreads();
    }
    const float lse = redm[0] + logf(reds[0]);

    // normalize exactly the rows this block wrote in phase B
    const int rbeg = ((blockIdx.x * NGROUPS) >> 10) * 4;
    const int rend = (((blockIdx.x + 1) * NGROUPS) >> 10) * 4;
    for (int r = rbeg + tid; r < rend; r += 256) {
      d_out[r] -= lse;
    }
  }
}

extern "C" void kernel_launch(void* const* d_in, const int* in_sizes, int n_in,
                              void* d_out, int out_size, void* d_ws, size_t ws_size,
                              hipStream_t stream) {
  const int*   ids    = (const int*)d_in[0];
  const float* hidden = (const float*)d_in[1];
  const float* emb    = (const float*)d_in[2];
  const float* W_ih   = (const float*)d_in[3];
  const float* W_hh   = (const float*)d_in[4];
  const float* b_ih   = (const float*)d_in[5];
  const float* b_hh   = (const float*)d_in[6];
  const float* W_out  = (const float*)d_in[7];
  const float* b_out  = (const float*)d_in[8];
  float* out = (float*)d_out;
  float* ws  = (float*)d_ws;

  // zero the two barrier counters (graph-capturable stream op)
  hipMemsetAsync(ws + WS_BAR, 0, 2 * sizeof(unsigned int), stream);

  decoder_fused<<<NBLK, 256, 0, stream>>>(ids, hidden, emb, W_ih, W_hh,
                                          b_ih, b_hh, W_out, b_out, out, ws);
}

// Round 9
// 97.203 us; speedup vs baseline: 4.4564x; 4.4564x over previous
//
#include <hip/hip_runtime.h>
#include <math.h>

#define H 1024
#define V 128000
#define G3H 3072     // 3*H

#define K2_BLOCKS 1024
#define K2_WAVES  (K2_BLOCKS * 4)   // 4096 waves, all co-resident
#define K2_GROUPS (V / 4)           // 32000 groups of 4 rows
#define NPART     K2_BLOCKS         // one (m,S) pair per block

// ws layout (floats):
//   [0 .. 6143]           gi (3072) then gh (3072)
//   [8192 .. 8192+2047]   per-block (m, S) partials for LSE
#define WS_GI   0
#define WS_GH   G3H
#define WS_PART 8192

typedef float f32x4 __attribute__((ext_vector_type(4)));

#define DOT4(w_, x_) fmaf((w_).x,(x_).x, fmaf((w_).y,(x_).y, fmaf((w_).z,(x_).z, (w_).w*(x_).w)))

__device__ __forceinline__ float sigmoid_fast(float x) {
  return 1.f / (1.f + __expf(-x));
}
__device__ __forceinline__ float tanh_fast(float x) {
  // tanh(x) = 1 - 2/(e^{2x}+1); overflow-safe (inf -> 1, 0 -> -1)
  return 1.f - 2.f / (__expf(2.f * x) + 1.f);
}

// ================= K1: gates =================
// gi = W_ih @ relu(emb[id]) + b_ih ; gh = W_hh @ h0 + b_hh
// 768 blocks x 256 threads = 3072 waves; each wave handles 2 consecutive rows.
__global__ __launch_bounds__(256) void gates_matvec(
    const int* __restrict__ ids, const float* __restrict__ hidden,
    const float* __restrict__ emb,
    const float* __restrict__ W_ih, const float* __restrict__ W_hh,
    const float* __restrict__ b_ih, const float* __restrict__ b_hh,
    float* __restrict__ ws) {
  const int tid  = threadIdx.x;
  const int lane = tid & 63;
  const int wid  = blockIdx.x * 4 + (tid >> 6);   // 0..3071
  const bool isGi = (wid < 1536);
  const int row0 = (isGi ? wid : wid - 1536) * 2;

  const float* Wm = isGi ? W_ih : W_hh;
  const float* xp = isGi ? (emb + (size_t)ids[0] * H) : hidden;

  f32x4 x0 = ((const f32x4*)xp)[lane];
  f32x4 x1 = ((const f32x4*)xp)[lane + 64];
  f32x4 x2 = ((const f32x4*)xp)[lane + 128];
  f32x4 x3 = ((const f32x4*)xp)[lane + 192];
  if (isGi) {
    x0.x=fmaxf(x0.x,0.f); x0.y=fmaxf(x0.y,0.f); x0.z=fmaxf(x0.z,0.f); x0.w=fmaxf(x0.w,0.f);
    x1.x=fmaxf(x1.x,0.f); x1.y=fmaxf(x1.y,0.f); x1.z=fmaxf(x1.z,0.f); x1.w=fmaxf(x1.w,0.f);
    x2.x=fmaxf(x2.x,0.f); x2.y=fmaxf(x2.y,0.f); x2.z=fmaxf(x2.z,0.f); x2.w=fmaxf(x2.w,0.f);
    x3.x=fmaxf(x3.x,0.f); x3.y=fmaxf(x3.y,0.f); x3.z=fmaxf(x3.z,0.f); x3.w=fmaxf(x3.w,0.f);
  }

  const f32x4* wa = (const f32x4*)(Wm + (size_t)row0 * H);
  const f32x4* wb = (const f32x4*)(Wm + (size_t)(row0 + 1) * H);
  const f32x4 a0 = __builtin_nontemporal_load(wa + lane);
  const f32x4 a1 = __builtin_nontemporal_load(wa + lane + 64);
  const f32x4 a2 = __builtin_nontemporal_load(wa + lane + 128);
  const f32x4 a3 = __builtin_nontemporal_load(wa + lane + 192);
  const f32x4 b0 = __builtin_nontemporal_load(wb + lane);
  const f32x4 b1 = __builtin_nontemporal_load(wb + lane + 64);
  const f32x4 b2 = __builtin_nontemporal_load(wb + lane + 128);
  const f32x4 b3 = __builtin_nontemporal_load(wb + lane + 192);
  float pa = (DOT4(a0,x0) + DOT4(a1,x1)) + (DOT4(a2,x2) + DOT4(a3,x3));
  float pb = (DOT4(b0,x0) + DOT4(b1,x1)) + (DOT4(b2,x2) + DOT4(b3,x3));
#pragma unroll
  for (int off = 1; off < 64; off <<= 1) {
    pa += __shfl_xor(pa, off);
    pb += __shfl_xor(pb, off);
  }
  if (lane < 2) {
    const int row = row0 + lane;
    const float s = (lane == 0) ? pa : pb;
    if (isGi) ws[WS_GI + row] = s + b_ih[row];
    else      ws[WS_GH + row] = s + b_hh[row];
  }
}

// ================= K2: persistent logits + per-block LSE partials =================
// 1024 blocks x 256 threads, all co-resident. Balanced contiguous ranges:
// wave w owns groups [w*32000>>12, (w+1)*32000>>12) -> 7 or 8 each.
__global__ __launch_bounds__(256, 4) void logits_lse(
    const float* __restrict__ hidden, const float* __restrict__ ws_in,
    const float* __restrict__ W_out, const float* __restrict__ b_out,
    float* __restrict__ d_out, float* __restrict__ ws_part) {
  __shared__ __align__(16) f32x4 h1s4[256];
  __shared__ float wpm[4], wps[4];
  const int tid = threadIdx.x;

  // --- h1 recompute: 1 quad/thread, fast transcendentals ---
  {
    const f32x4* ws4 = (const f32x4*)ws_in;
    const f32x4 gi0 = ws4[tid];          // gi[0:H]
    const f32x4 gi1 = ws4[tid + 256];    // gi[H:2H]
    const f32x4 gi2 = ws4[tid + 512];    // gi[2H:3H]
    const f32x4 gh0 = ws4[tid + 768];    // gh[0:H]
    const f32x4 gh1 = ws4[tid + 1024];   // gh[H:2H]
    const f32x4 gh2 = ws4[tid + 1280];   // gh[2H:3H]
    const f32x4 h0v = ((const f32x4*)hidden)[tid];
    f32x4 h1;
#pragma unroll
    for (int j = 0; j < 4; ++j) {
      const float r = sigmoid_fast(gi0[j] + gh0[j]);
      const float z = sigmoid_fast(gi1[j] + gh1[j]);
      const float n = tanh_fast(gi2[j] + r * gh2[j]);
      h1[j] = (1.f - z) * n + z * h0v[j];
    }
    h1s4[tid] = h1;
  }
  __syncthreads();
  if (blockIdx.x == 0) {
    ((f32x4*)(d_out + V))[tid] = h1s4[tid];
  }

  const int lane = tid & 63;
  const int wid  = blockIdx.x * 4 + (tid >> 6);   // 0..4095
  const int gbeg = (wid * K2_GROUPS) >> 12;       // /4096
  const int gend = ((wid + 1) * K2_GROUPS) >> 12;

  const f32x4 x0 = h1s4[lane];
  const f32x4 x1 = h1s4[lane + 64];
  const f32x4 x2 = h1s4[lane + 128];
  const f32x4 x3 = h1s4[lane + 192];

  float m = -INFINITY, S = 0.f;

#pragma unroll 1
  for (int g = gbeg; g < gend; ++g) {
    const int row0 = g * 4;
    const f32x4* w = (const f32x4*)(W_out + (size_t)row0 * H);  // 4 rows x 256 quads

    const f32x4 a0 = __builtin_nontemporal_load(w + lane);
    const f32x4 a1 = __builtin_nontemporal_load(w + lane + 64);
    const f32x4 a2 = __builtin_nontemporal_load(w + lane + 128);
    const f32x4 a3 = __builtin_nontemporal_load(w + lane + 192);
    const f32x4 b0 = __builtin_nontemporal_load(w + lane + 256);
    const f32x4 b1 = __builtin_nontemporal_load(w + lane + 320);
    const f32x4 b2 = __builtin_nontemporal_load(w + lane + 384);
    const f32x4 b3 = __builtin_nontemporal_load(w + lane + 448);
    const f32x4 c0 = __builtin_nontemporal_load(w + lane + 512);
    const f32x4 c1 = __builtin_nontemporal_load(w + lane + 576);
    const f32x4 c2 = __builtin_nontemporal_load(w + lane + 640);
    const f32x4 c3 = __builtin_nontemporal_load(w + lane + 704);
    const f32x4 d0 = __builtin_nontemporal_load(w + lane + 768);
    const f32x4 d1 = __builtin_nontemporal_load(w + lane + 832);
    const f32x4 d2 = __builtin_nontemporal_load(w + lane + 896);
    const f32x4 d3 = __builtin_nontemporal_load(w + lane + 960);

    float p0 = (DOT4(a0,x0) + DOT4(a1,x1)) + (DOT4(a2,x2) + DOT4(a3,x3));
    float p1 = (DOT4(b0,x0) + DOT4(b1,x1)) + (DOT4(b2,x2) + DOT4(b3,x3));
    float p2 = (DOT4(c0,x0) + DOT4(c1,x1)) + (DOT4(c2,x2) + DOT4(c3,x3));
    float p3 = (DOT4(d0,x0) + DOT4(d1,x1)) + (DOT4(d2,x2) + DOT4(d3,x3));

#pragma unroll
    for (int off = 1; off < 64; off <<= 1) {
      p0 += __shfl_xor(p0, off);
      p1 += __shfl_xor(p1, off);
      p2 += __shfl_xor(p2, off);
      p3 += __shfl_xor(p3, off);
    }

    const float4 bo = *(const float4*)(b_out + row0);
    const float l0 = p0 + bo.x, l1 = p1 + bo.y, l2 = p2 + bo.z, l3 = p3 + bo.w;

    const float sel = (lane == 0) ? l0 : (lane == 1) ? l1 : (lane == 2) ? l2 : l3;
    if (lane < 4) d_out[row0 + lane] = sel;

    const float m4 = fmaxf(fmaxf(l0, l1), fmaxf(l2, l3));
    const float mn = fmaxf(m, m4);
    S = S * __expf(m - mn)
      + __expf(l0 - mn) + __expf(l1 - mn) + __expf(l2 - mn) + __expf(l3 - mn);
    m = mn;
  }

  // combine the block's 4 wave partials through LDS -> 1 pair per block
  if (lane == 0) { wpm[tid >> 6] = m; wps[tid >> 6] = S; }
  __syncthreads();
  if (tid == 0) {
    float bm = wpm[0], bS = wps[0];
#pragma unroll
    for (int k = 1; k < 4; ++k) {
      const float mk = wpm[k], sk = wps[k];
      const float mn = fmaxf(bm, mk);
      bS = bS * __expf(bm - mn) + sk * __expf(mk - mn);
      bm = mn;
    }
    ws_part[2 * blockIdx.x]     = bm;
    ws_part[2 * blockIdx.x + 1] = bS;
  }
}

// ================= K3: combine partials + normalize in place =================
// 500 blocks x 256; every block redundantly folds the 1024 (m,S) pairs
// (8 KB, L2-resident), then normalizes its own 256 logits.
__global__ __launch_bounds__(256) void lse_norm(
    float* __restrict__ d_out, const float* __restrict__ ws_part) {
  __shared__ float redm[256], reds[256];
  const int tid = threadIdx.x;

  float m = -INFINITY, S = 0.f;
  for (int b = tid; b < NPART; b += 256) {   // 4 iterations
    const float mb = ws_part[2*b], sb = ws_part[2*b+1];
    const float mn = fmaxf(m, mb);
    S = S * __expf(m - mn) + sb * __expf(mb - mn);
    m = mn;
  }
  redm[tid] = m; reds[tid] = S;
  __syncthreads();
  for (int s = 128; s > 0; s >>= 1) {
    if (tid < s) {
      const float m2 = redm[tid + s], s2 = reds[tid + s];
      const float mn = fmaxf(redm[tid], m2);
      reds[tid] = reds[tid] * __expf(redm[tid] - mn) + s2 * __expf(m2 - mn);
      redm[tid] = mn;
    }
    __syncthreads();
  }
  const float lse = redm[0] + logf(reds[0]);

  const int i = blockIdx.x * 256 + tid;   // 500*256 == V exactly
  d_out[i] -= lse;
}

extern "C" void kernel_launch(void* const* d_in, const int* in_sizes, int n_in,
                              void* d_out, int out_size, void* d_ws, size_t ws_size,
                              hipStream_t stream) {
  const int*   ids    = (const int*)d_in[0];
  const float* hidden = (const float*)d_in[1];
  const float* emb    = (const float*)d_in[2];
  const float* W_ih   = (const float*)d_in[3];
  const float* W_hh   = (const float*)d_in[4];
  const float* b_ih   = (const float*)d_in[5];
  const float* b_hh   = (const float*)d_in[6];
  const float* W_out  = (const float*)d_in[7];
  const float* b_out  = (const float*)d_in[8];
  float* out = (float*)d_out;
  float* ws  = (float*)d_ws;

  gates_matvec<<<768, 256, 0, stream>>>(ids, hidden, emb, W_ih, W_hh, b_ih, b_hh, ws);
  logits_lse<<<K2_BLOCKS, 256, 0, stream>>>(hidden, ws, W_out, b_out, out, ws + WS_PART);
  lse_norm<<<500, 256, 0, stream>>>(out, ws + WS_PART);
}